// Round 5
// baseline (390.639 us; speedup 1.0000x reference)
//
#include <hip/hip_runtime.h>
#include <cstdint>

#define NUM_USERS 50000
#define NUM_ITEMS 40000
#define EMB 64
#define NNZ_E 2000000
#define BATCH 1024
#define NCHB 125           // 40000 / 320 col blocks for k_xz (exact)
#define SLOT_CAP 128       // edges per batch slot (E[40])
#define INF_I 0x7fffffff

typedef __attribute__((ext_vector_type(8))) short short8;   // 8 x bf16 (4 VGPRs)
typedef __attribute__((ext_vector_type(4))) float float4v;  // MFMA C/D

__device__ __forceinline__ unsigned short f2bf(float f) {
    union { float f; unsigned u; } x; x.f = f;
    unsigned r = x.u + 0x7fffu + ((x.u >> 16) & 1u);
    return (unsigned short)(r >> 16);
}
__device__ __forceinline__ float bf2f(unsigned short s) {
    return __uint_as_float(((unsigned)s) << 16);
}
// pack hi16(lo), hi16(hi) -> one u32 of 2 bf16 (EXACT for x in {0,1})
__device__ __forceinline__ unsigned pack01(float lo, float hi) {
    return __builtin_amdgcn_perm(__float_as_uint(hi), __float_as_uint(lo), 0x07060302u);
}

// ---------------- init: map=INF; cnt/scal/compact = 0 ----------------
__global__ __launch_bounds__(256) void k_init(int* __restrict__ map, int* __restrict__ cnt,
                                              float* __restrict__ scal, int2* __restrict__ compact) {
    int t = blockIdx.x * blockDim.x + threadIdx.x;
    if (t < NUM_USERS) map[t] = INF_I;
    if (t < BATCH) cnt[t] = 0;
    if (t < 4) scal[t] = 0.f;          // [0] recon, [1] kl, [2] done-counter, [3] spare
    if (t < BATCH * SLOT_CAP) compact[t] = make_int2(0, 0);   // zero-pad for k_hz unroll
}

__global__ void k_map(const int* __restrict__ user, int* __restrict__ map) {
    int i = blockIdx.x * blockDim.x + threadIdx.x;
    if (i < BATCH) atomicMin(&map[user[i]], i);
}

// ---------------- scatter: standalone, zero LDS -> full occupancy ----------------
__global__ __launch_bounds__(256) void k_scatter(const int* __restrict__ rows,
                                                 const int* __restrict__ cols,
                                                 const float* __restrict__ vals,
                                                 const int* __restrict__ map,
                                                 int* __restrict__ cnt,
                                                 int2* __restrict__ compact) {
    const int e = blockIdx.x * 256 + threadIdx.x;
    if (e >= NNZ_E) return;
    int s = map[rows[e]];
    if (s == INF_I) return;
    int pos = atomicAdd(&cnt[s], 1);
    if (pos < SLOT_CAP) compact[s * SLOT_CAP + pos] = make_int2(cols[e], __float_as_int(vals[e]));
}

// ---------------- prep: WqT transpose | WpBf cvt | WpT transpose | bpBf ----------------
// LDS capped at 4224 floats (16.9 KB) -> 9 blocks/CU (was 41.6 KB -> 3/CU).
__global__ __launch_bounds__(256) void k_prep(const float* __restrict__ Wq,
                                              const float* __restrict__ Wp,
                                              const float* __restrict__ bp,
                                              unsigned short* __restrict__ WqT,
                                              unsigned short* __restrict__ WpBf,
                                              unsigned short* __restrict__ WpT,
                                              unsigned short* __restrict__ bpBf) {
    __shared__ float t2f[4224];         // max(128*33, 64*65)
    const int bid = blockIdx.x;
    const int tid = threadIdx.x;
    if (bid < 1250) {                   // WqT: (128 x 40000) -> (40000 x 128) bf16
        const int jb = bid * 32;
        for (int idx = tid; idx < 4096; idx += 256) {
            int d = idx >> 5, c = idx & 31;
            t2f[d * 33 + c] = Wq[(size_t)d * NUM_ITEMS + jb + c];
        }
        __syncthreads();
        for (int idx = tid; idx < 4096; idx += 256) {
            int j = idx >> 7, d = idx & 127;
            WqT[(size_t)(jb + j) * 128 + d] = f2bf(t2f[d * 33 + j]);
        }
    } else if (bid < 3750) {            // WpBf: row-major bf16 copy of Wp
        const int e0 = ((bid - 1250) * 256 + tid) * 4;
        float4 w = *(const float4*)&Wp[e0];
        ushort4 o;
        o.x = f2bf(w.x); o.y = f2bf(w.y); o.z = f2bf(w.z); o.w = f2bf(w.w);
        *(ushort4*)&WpBf[e0] = o;
    } else if (bid < 4375) {            // WpT: (40000 x 64) -> (64 x 40000) bf16, 64-row tiles
        const int j0 = (bid - 3750) * 64;
        for (int idx = tid; idx < 4096; idx += 256) {
            int jl = idx >> 6, d = idx & 63;
            t2f[jl * 65 + d] = Wp[(size_t)(j0 + jl) * 64 + d];
        }
        __syncthreads();
        for (int idx = tid; idx < 4096; idx += 256) {
            int d = idx >> 6, jl = idx & 63;
            WpT[(size_t)d * NUM_ITEMS + j0 + jl] = f2bf(t2f[jl * 65 + d]);
        }
    } else {                            // bpBf: bf16 copy of bp
        const int e0 = ((bid - 4375) * 256 + tid) * 4;
        if (e0 < NUM_ITEMS) {
            float4 w = *(const float4*)&bp[e0];
            ushort4 o;
            o.x = f2bf(w.x); o.y = f2bf(w.y); o.z = f2bf(w.z); o.w = f2bf(w.w);
            *(ushort4*)&bpBf[e0] = o;
        }
    }
}

// ---------------- h + z + KL: 4 waves split edges, ushort2 gathers ----------------
__global__ __launch_bounds__(256) void k_hz(const int* __restrict__ user,
                                            const int* __restrict__ map,
                                            const int* __restrict__ cnt,
                                            const int2* __restrict__ compact,
                                            const unsigned short* __restrict__ WqT,
                                            const float* __restrict__ bq,
                                            const float* __restrict__ eps,
                                            unsigned short* __restrict__ zbBf,
                                            float* __restrict__ zF32,
                                            float* __restrict__ scal) {
    __shared__ float sh[4][128];
    const int i = blockIdx.x;
    const int tid = threadIdx.x;
    const int w = tid >> 6, lane = tid & 63;
    const int u = user[i];
    const int s = map[u];
    const int n8 = (min(cnt[s], SLOT_CAP) + 7) & ~7;   // compact zero-padded -> safe
    const int2* cp = compact + s * SLOT_CAP;
    float ax = 0.f, ay = 0.f;
    for (int e = w; e < n8; e += 8) {
        int2 c0 = cp[e], c1 = cp[e + 4];
        ushort2 w0 = *(const ushort2*)&WqT[(size_t)c0.x * 128 + lane * 2];
        ushort2 w1 = *(const ushort2*)&WqT[(size_t)c1.x * 128 + lane * 2];
        float v0 = __int_as_float(c0.y), v1 = __int_as_float(c1.y);
        ax = fmaf(v0, bf2f(w0.x), ax);
        ay = fmaf(v0, bf2f(w0.y), ay);
        ax = fmaf(v1, bf2f(w1.x), ax);
        ay = fmaf(v1, bf2f(w1.y), ay);
    }
    sh[w][lane * 2] = ax;
    sh[w][lane * 2 + 1] = ay;
    __syncthreads();
    float h = 0.f;
    if (tid < 128) h = sh[0][tid] + sh[1][tid] + sh[2][tid] + sh[3][tid] + bq[tid];
    __syncthreads();
    if (tid < 128) sh[0][tid] = h;
    __syncthreads();
    if (tid < 64) {
        float mu = sh[0][tid];
        float lv = sh[0][tid + 64];
        float z = fmaf(eps[(size_t)u * EMB + tid], __expf(0.5f * lv), mu);
        zbBf[i * EMB + tid] = f2bf(z);
        zF32[i * EMB + tid] = z;
        float kl = 1.0f + lv - mu * mu - __expf(lv);
        #pragma unroll
        for (int o = 32; o; o >>= 1) kl += __shfl_down(kl, o);
        if (tid == 0) atomicAdd(&scal[1], kl);
    }
}

// ---------------- fused x-GEMM + z-LSE, 1-wave blocks for occupancy ----------------
// grid (125, 32); block = 1 wave = 32 rows; col chunk = 320 items.
// Phase A: X @ [Wp | bp | ones] -> dx = z.(X@Wp), sx = X@1, xb = X@bp.
// Phase B: online-softmax LSE of z @ Wp^T + bp over the same 320 cols.
// One float4 partial (m, s, dx+xb, sx) per (row, chunk).
__global__ __launch_bounds__(64) void k_xz(const float* __restrict__ x,
                                           const unsigned short* __restrict__ WpT,
                                           const unsigned short* __restrict__ bpBf,
                                           const float* __restrict__ zF32,
                                           const unsigned short* __restrict__ zbBf,
                                           const unsigned short* __restrict__ WpBf,
                                           const float* __restrict__ bp,
                                           float4* __restrict__ part4) {
    const int lane = threadIdx.x;
    const int l15 = lane & 15, quad = lane >> 4;
    const int kc = blockIdx.x;
    const int ibase = blockIdx.y * 32;

    // ---------- phase A: x-GEMM ----------
    float4v acc[2][4], accA[2];
    #pragma unroll
    for (int mt = 0; mt < 2; mt++) {
        accA[mt] = (float4v){0.f, 0.f, 0.f, 0.f};
        #pragma unroll
        for (int nt = 0; nt < 4; nt++) acc[mt][nt] = (float4v){0.f, 0.f, 0.f, 0.f};
    }
    #pragma unroll
    for (int st = 0; st < 10; st++) {
        const int kb = kc * 320 + st * 32;
        short8 af[2];
        #pragma unroll
        for (int mt = 0; mt < 2; mt++) {
            const float* px = x + (size_t)(ibase + mt * 16 + l15) * NUM_ITEMS + kb + quad * 8;
            float4 a0 = *(const float4*)px;
            float4 a1 = *(const float4*)(px + 4);
            union { short8 s; unsigned u[4]; } v;
            v.u[0] = pack01(a0.x, a0.y);
            v.u[1] = pack01(a0.z, a0.w);
            v.u[2] = pack01(a1.x, a1.y);
            v.u[3] = pack01(a1.z, a1.w);
            af[mt] = v.s;
        }
        short8 bfr[4];
        #pragma unroll
        for (int nt = 0; nt < 4; nt++)
            bfr[nt] = *(const short8*)&WpT[(size_t)(nt * 16 + l15) * NUM_ITEMS + kb + quad * 8];
        short8 ab;
        if (l15 == 0) {
            ab = *(const short8*)&bpBf[kb + quad * 8];
        } else if (l15 == 1) {
            short o = (short)0x3F80;                 // bf16 1.0
            ab = (short8){o, o, o, o, o, o, o, o};
        } else {
            ab = (short8){0, 0, 0, 0, 0, 0, 0, 0};
        }
        #pragma unroll
        for (int mt = 0; mt < 2; mt++) {
            #pragma unroll
            for (int nt = 0; nt < 4; nt++)
                acc[mt][nt] = __builtin_amdgcn_mfma_f32_16x16x32_bf16(
                    af[mt], bfr[nt], acc[mt][nt], 0, 0, 0);
            accA[mt] = __builtin_amdgcn_mfma_f32_16x16x32_bf16(
                    af[mt], ab, accA[mt], 0, 0, 0);
        }
    }
    // epilogue A: dx = z.Y reduced over l15; sx from ones col; xb from bp col
    float c_s[2][4], sx_s[2][4];
    #pragma unroll
    for (int mt = 0; mt < 2; mt++) {
        #pragma unroll
        for (int r = 0; r < 4; r++) {
            const int row = ibase + mt * 16 + quad * 4 + r;
            float dxp = 0.f;
            #pragma unroll
            for (int nt = 0; nt < 4; nt++)
                dxp += zF32[(size_t)row * EMB + nt * 16 + l15] * acc[mt][nt][r];
            #pragma unroll
            for (int d = 1; d < 16; d <<= 1) dxp += __shfl_xor(dxp, d);
            sx_s[mt][r] = __shfl(accA[mt][r], (lane & 48) + 1);   // col 1 = ones
            c_s[mt][r] = dxp + accA[mt][r];                       // + col 0 (bp) at l15==0
        }
    }

    // ---------- phase B: z-LSE ----------
    short8 zf[2][2];
    #pragma unroll
    for (int mt = 0; mt < 2; mt++) {
        const unsigned short* pa = zbBf + (size_t)(ibase + mt * 16 + l15) * EMB + quad * 8;
        zf[mt][0] = *(const short8*)pa;
        zf[mt][1] = *(const short8*)(pa + 32);
    }
    float m_run[2][4], s_run[2][4];
    #pragma unroll
    for (int mt = 0; mt < 2; mt++)
        #pragma unroll
        for (int r = 0; r < 4; r++) { m_run[mt][r] = -1e30f; s_run[mt][r] = 0.f; }

    #pragma unroll
    for (int c5 = 0; c5 < 5; c5++) {
        const int jb = kc * 320 + c5 * 64;
        short8 bfr2[4][2];
        #pragma unroll
        for (int nt = 0; nt < 4; nt++) {
            const unsigned short* pb = WpBf + (size_t)(jb + nt * 16 + l15) * EMB + quad * 8;
            bfr2[nt][0] = *(const short8*)pb;
            bfr2[nt][1] = *(const short8*)(pb + 32);
        }
        float4v accz[2][4];
        #pragma unroll
        for (int mt = 0; mt < 2; mt++)
            #pragma unroll
            for (int nt = 0; nt < 4; nt++)
                accz[mt][nt] = (float4v){0.f, 0.f, 0.f, 0.f};
        #pragma unroll
        for (int kh = 0; kh < 2; kh++)
            #pragma unroll
            for (int mt = 0; mt < 2; mt++)
                #pragma unroll
                for (int nt = 0; nt < 4; nt++)
                    accz[mt][nt] = __builtin_amdgcn_mfma_f32_16x16x32_bf16(
                        zf[mt][kh], bfr2[nt][kh], accz[mt][nt], 0, 0, 0);
        float bpv[4];
        #pragma unroll
        for (int nt = 0; nt < 4; nt++) bpv[nt] = bp[jb + nt * 16 + l15];
        #pragma unroll
        for (int mt = 0; mt < 2; mt++) {
            #pragma unroll
            for (int r = 0; r < 4; r++) {
                float v0 = accz[mt][0][r] + bpv[0];
                float v1 = accz[mt][1][r] + bpv[1];
                float v2 = accz[mt][2][r] + bpv[2];
                float v3 = accz[mt][3][r] + bpv[3];
                float mx = fmaxf(fmaxf(v0, v1), fmaxf(v2, v3));
                float M2 = fmaxf(m_run[mt][r], mx);
                float ls = __expf(v0 - M2) + __expf(v1 - M2) +
                           __expf(v2 - M2) + __expf(v3 - M2);
                s_run[mt][r] = s_run[mt][r] * __expf(m_run[mt][r] - M2) + ls;
                m_run[mt][r] = M2;
            }
        }
    }
    #pragma unroll
    for (int d = 1; d < 16; d <<= 1) {
        #pragma unroll
        for (int mt = 0; mt < 2; mt++)
            #pragma unroll
            for (int r = 0; r < 4; r++) {
                float m2 = __shfl_xor(m_run[mt][r], d);
                float s2 = __shfl_xor(s_run[mt][r], d);
                float M = fmaxf(m_run[mt][r], m2);
                s_run[mt][r] = s_run[mt][r] * __expf(m_run[mt][r] - M)
                             + s2 * __expf(m2 - M);
                m_run[mt][r] = M;
            }
    }
    if (l15 == 0) {
        #pragma unroll
        for (int mt = 0; mt < 2; mt++)
            #pragma unroll
            for (int r = 0; r < 4; r++) {
                const int row = ibase + mt * 16 + quad * 4 + r;
                part4[(size_t)row * NCHB + kc] =
                    make_float4(m_run[mt][r], s_run[mt][r], c_s[mt][r], sx_s[mt][r]);
            }
    }
}

// ---------------- merge: lse per row + loss; last block writes out ----------------
__global__ __launch_bounds__(64) void k_merge(const float4* __restrict__ part4,
                                              float* __restrict__ scal,
                                              float* __restrict__ out) {
    const int row = blockIdx.x;
    const int lane = threadIdx.x;
    float M = -1e30f, S = 0.f, dxc = 0.f, sx = 0.f;
    for (int c = lane; c < NCHB; c += 64) {
        float4 p = part4[(size_t)row * NCHB + c];
        float M2 = fmaxf(M, p.x);
        S = S * __expf(M - M2) + p.y * __expf(p.x - M2);
        M = M2; dxc += p.z; sx += p.w;
    }
    #pragma unroll
    for (int o = 1; o < 64; o <<= 1) {
        float M2 = __shfl_xor(M, o);
        float S2 = __shfl_xor(S, o);
        float Mn = fmaxf(M, M2);
        S = S * __expf(M - Mn) + S2 * __expf(M2 - Mn);
        M = Mn;
        dxc += __shfl_xor(dxc, o);
        sx += __shfl_xor(sx, o);
    }
    if (lane == 0) {
        float lse = M + logf(S);
        atomicAdd(&scal[0], dxc - lse * sx);
        __threadfence();
        unsigned done = atomicAdd((unsigned*)&scal[2], 1u);
        if (done == BATCH - 1) {
            float recon = atomicAdd(&scal[0], 0.f);
            float kl = atomicAdd(&scal[1], 0.f);
            out[0] = -recon * (1.0f / BATCH);
            out[1] = -0.5f * kl * (1.0f / BATCH);
        }
    }
}

extern "C" void kernel_launch(void* const* d_in, const int* in_sizes, int n_in,
                              void* d_out, int out_size, void* d_ws, size_t ws_size,
                              hipStream_t stream) {
    const float* graph_vals = (const float*)d_in[0];
    const float* Wq         = (const float*)d_in[1];
    const float* bq         = (const float*)d_in[2];
    const float* Wp         = (const float*)d_in[3];
    const float* bp         = (const float*)d_in[4];
    const float* x          = (const float*)d_in[5];
    const float* eps        = (const float*)d_in[6];
    const int*   graph_rows = (const int*)d_in[7];
    const int*   graph_cols = (const int*)d_in[8];
    const int*   user       = (const int*)d_in[9];
    float* out = (float*)d_out;

    char* ws = (char*)d_ws;
    int*            map     = (int*)(ws + 0);                    //   200,704
    int*            cnt     = (int*)(ws + 200704);               //     4,096
    float*          scal    = (float*)(ws + 204800);             //       256
    int2*           compact = (int2*)(ws + 205056);              // 1,048,576 -> 1,253,632
    unsigned short* zbBf    = (unsigned short*)(ws + 1253632);   //   131,072 -> 1,384,704
    float*          zF32    = (float*)(ws + 1384704);            //   262,144 -> 1,646,848
    float4*         part4   = (float4*)(ws + 1646848);           // 2,048,000 -> 3,694,848
    unsigned short* WpBf    = (unsigned short*)(ws + 3694848);   // 5,120,000 -> 8,814,848
    unsigned short* WqT     = (unsigned short*)(ws + 8814848);   // 10,240,000 -> 19,054,848
    unsigned short* WpT     = (unsigned short*)(ws + 19054848);  // 5,120,000 -> 24,174,848
    unsigned short* bpBf    = (unsigned short*)(ws + 24174848);  //    80,000 -> 24,254,848

    k_init<<<512, 256, 0, stream>>>(map, cnt, scal, compact);
    k_map<<<4, 256, 0, stream>>>(user, map);
    k_scatter<<<7813, 256, 0, stream>>>(graph_rows, graph_cols, graph_vals, map, cnt, compact);
    k_prep<<<4415, 256, 0, stream>>>(Wq, Wp, bp, WqT, WpBf, WpT, bpBf);
    k_hz<<<BATCH, 256, 0, stream>>>(user, map, cnt, compact, WqT, bq, eps, zbBf, zF32, scal);
    dim3 g(NCHB, 32);
    k_xz<<<g, 64, 0, stream>>>(x, WpT, bpBf, zF32, zbBf, WpBf, bp, part4);
    k_merge<<<BATCH, 64, 0, stream>>>(part4, scal, out);
}

// Round 6
// 378.764 us; speedup vs baseline: 1.0314x; 1.0314x over previous
//
#include <hip/hip_runtime.h>
#include <cstdint>

#define NUM_USERS 50000
#define NUM_ITEMS 40000
#define EMB 64
#define NNZ_E 2000000
#define BATCH 1024
#define NCHB 125           // 40000 / 320 col blocks for k_xz (exact)
#define SLOT_CAP 128       // edges per batch slot (E[40])
#define INF_I 0x7fffffff
#define SC_BLK 7813        // scatter blocks inside k_prepsc

typedef __attribute__((ext_vector_type(8))) short short8;   // 8 x bf16 (4 VGPRs)
typedef __attribute__((ext_vector_type(4))) float float4v;  // MFMA C/D

__device__ __forceinline__ unsigned short f2bf(float f) {
    union { float f; unsigned u; } x; x.f = f;
    unsigned r = x.u + 0x7fffu + ((x.u >> 16) & 1u);
    return (unsigned short)(r >> 16);
}
__device__ __forceinline__ float bf2f(unsigned short s) {
    return __uint_as_float(((unsigned)s) << 16);
}
// pack hi16(lo), hi16(hi) -> one u32 of 2 bf16 (EXACT for x in {0,1})
__device__ __forceinline__ unsigned pack01(float lo, float hi) {
    return __builtin_amdgcn_perm(__float_as_uint(hi), __float_as_uint(lo), 0x07060302u);
}

// ---------------- init: map=INF; cnt/scal/compact = 0 ----------------
__global__ __launch_bounds__(256) void k_init(int* __restrict__ map, int* __restrict__ cnt,
                                              float* __restrict__ scal, int2* __restrict__ compact) {
    int t = blockIdx.x * blockDim.x + threadIdx.x;
    if (t < NUM_USERS) map[t] = INF_I;
    if (t < BATCH) cnt[t] = 0;
    if (t < 4) scal[t] = 0.f;          // [0] recon, [1] kl, [2] done-counter, [3] spare
    if (t < BATCH * SLOT_CAP) compact[t] = make_int2(0, 0);   // zero-pad for k_hz unroll
}

__global__ void k_map(const int* __restrict__ user, int* __restrict__ map) {
    int i = blockIdx.x * blockDim.x + threadIdx.x;
    if (i < BATCH) atomicMin(&map[user[i]], i);
}

// ---------------- fused scatter + prep ----------------
// LDS = 16.9 KB (not occupancy-binding for 256-thr blocks: thread limit = 8 blocks/CU).
// First SC_BLK blocks: edge scatter (no LDS touch). Rest: weight transposes/casts.
__global__ __launch_bounds__(256) void k_prepsc(const int* __restrict__ rows,
                                                const int* __restrict__ cols,
                                                const float* __restrict__ vals,
                                                const int* __restrict__ map,
                                                int* __restrict__ cnt,
                                                int2* __restrict__ compact,
                                                const float* __restrict__ Wq,
                                                const float* __restrict__ Wp,
                                                const float* __restrict__ bp,
                                                unsigned short* __restrict__ WqT,
                                                unsigned short* __restrict__ WpBf,
                                                unsigned short* __restrict__ WpT,
                                                unsigned short* __restrict__ bpBf) {
    __shared__ float t2f[4224];         // max(128*33, 64*65)
    const int bid = blockIdx.x;
    const int tid = threadIdx.x;
    if (bid < SC_BLK) {                 // edge scatter into per-slot bins
        const int e = bid * 256 + tid;
        if (e >= NNZ_E) return;
        int s = map[rows[e]];
        if (s == INF_I) return;
        int pos = atomicAdd(&cnt[s], 1);
        if (pos < SLOT_CAP) compact[s * SLOT_CAP + pos] = make_int2(cols[e], __float_as_int(vals[e]));
        return;
    }
    const int pb = bid - SC_BLK;
    if (pb < 1250) {                    // WqT: (128 x 40000) -> (40000 x 128) bf16
        const int jb = pb * 32;
        for (int idx = tid; idx < 4096; idx += 256) {
            int d = idx >> 5, c = idx & 31;
            t2f[d * 33 + c] = Wq[(size_t)d * NUM_ITEMS + jb + c];
        }
        __syncthreads();
        for (int idx = tid; idx < 4096; idx += 256) {
            int j = idx >> 7, d = idx & 127;
            WqT[(size_t)(jb + j) * 128 + d] = f2bf(t2f[d * 33 + j]);
        }
    } else if (pb < 3750) {             // WpBf: row-major bf16 copy of Wp
        const int e0 = ((pb - 1250) * 256 + tid) * 4;
        float4 w = *(const float4*)&Wp[e0];
        ushort4 o;
        o.x = f2bf(w.x); o.y = f2bf(w.y); o.z = f2bf(w.z); o.w = f2bf(w.w);
        *(ushort4*)&WpBf[e0] = o;
    } else if (pb < 4375) {             // WpT: (40000 x 64) -> (64 x 40000) bf16, 64-row tiles
        const int j0 = (pb - 3750) * 64;
        for (int idx = tid; idx < 4096; idx += 256) {
            int jl = idx >> 6, d = idx & 63;
            t2f[jl * 65 + d] = Wp[(size_t)(j0 + jl) * 64 + d];
        }
        __syncthreads();
        for (int idx = tid; idx < 4096; idx += 256) {
            int d = idx >> 6, jl = idx & 63;
            WpT[(size_t)d * NUM_ITEMS + j0 + jl] = f2bf(t2f[jl * 65 + d]);
        }
    } else {                            // bpBf: bf16 copy of bp
        const int e0 = ((pb - 4375) * 256 + tid) * 4;
        if (e0 < NUM_ITEMS) {
            float4 w = *(const float4*)&bp[e0];
            ushort4 o;
            o.x = f2bf(w.x); o.y = f2bf(w.y); o.z = f2bf(w.z); o.w = f2bf(w.w);
            *(ushort4*)&bpBf[e0] = o;
        }
    }
}

// ---------------- h + z + KL: 4 waves split edges, ushort2 gathers ----------------
__global__ __launch_bounds__(256) void k_hz(const int* __restrict__ user,
                                            const int* __restrict__ map,
                                            const int* __restrict__ cnt,
                                            const int2* __restrict__ compact,
                                            const unsigned short* __restrict__ WqT,
                                            const float* __restrict__ bq,
                                            const float* __restrict__ eps,
                                            unsigned short* __restrict__ zbBf,
                                            float* __restrict__ zF32,
                                            float* __restrict__ scal) {
    __shared__ float sh[4][128];
    const int i = blockIdx.x;
    const int tid = threadIdx.x;
    const int w = tid >> 6, lane = tid & 63;
    const int u = user[i];
    const int s = map[u];
    const int n8 = (min(cnt[s], SLOT_CAP) + 7) & ~7;   // compact zero-padded -> safe
    const int2* cp = compact + s * SLOT_CAP;
    float ax = 0.f, ay = 0.f;
    for (int e = w; e < n8; e += 8) {
        int2 c0 = cp[e], c1 = cp[e + 4];
        ushort2 w0 = *(const ushort2*)&WqT[(size_t)c0.x * 128 + lane * 2];
        ushort2 w1 = *(const ushort2*)&WqT[(size_t)c1.x * 128 + lane * 2];
        float v0 = __int_as_float(c0.y), v1 = __int_as_float(c1.y);
        ax = fmaf(v0, bf2f(w0.x), ax);
        ay = fmaf(v0, bf2f(w0.y), ay);
        ax = fmaf(v1, bf2f(w1.x), ax);
        ay = fmaf(v1, bf2f(w1.y), ay);
    }
    sh[w][lane * 2] = ax;
    sh[w][lane * 2 + 1] = ay;
    __syncthreads();
    float h = 0.f;
    if (tid < 128) h = sh[0][tid] + sh[1][tid] + sh[2][tid] + sh[3][tid] + bq[tid];
    __syncthreads();
    if (tid < 128) sh[0][tid] = h;
    __syncthreads();
    if (tid < 64) {
        float mu = sh[0][tid];
        float lv = sh[0][tid + 64];
        float z = fmaf(eps[(size_t)u * EMB + tid], __expf(0.5f * lv), mu);
        zbBf[i * EMB + tid] = f2bf(z);
        zF32[i * EMB + tid] = z;
        float kl = 1.0f + lv - mu * mu - __expf(lv);
        #pragma unroll
        for (int o = 32; o; o >>= 1) kl += __shfl_down(kl, o);
        if (tid == 0) atomicAdd(&scal[1], kl);
    }
}

// ---------------- fused x-GEMM + z-LSE with LDS-staged weights ----------------
// grid (125, 8); 256 thr = 4 waves x 32 rows. Per block the ONLY global loads in
// the hot loops are the x stream (2-deep prefetched). Weight slices staged once:
//   phase A: WpT slice [64][320] -> wlds [64][328]  (pad -> uniform 8/bank)
//   phase B: WpBf slice [320][64] -> wlds [320][72] (pad -> aligned + 8/bank)
__global__ __launch_bounds__(256) void k_xz(const float* __restrict__ x,
                                            const unsigned short* __restrict__ WpT,
                                            const unsigned short* __restrict__ bpBf,
                                            const float* __restrict__ zF32,
                                            const unsigned short* __restrict__ zbBf,
                                            const unsigned short* __restrict__ WpBf,
                                            const float* __restrict__ bp,
                                            float4* __restrict__ part4) {
    __shared__ unsigned short wlds[23040];   // max(64*328, 320*72) shorts = 46.1 KB
    __shared__ unsigned short bpblds[320];   // bf16 bp slice (phase A col-0 operand)
    __shared__ float bplds[320];             // f32 bp slice (phase B bias)
    const int tid = threadIdx.x;
    const int wid = tid >> 6, lane = tid & 63;
    const int l15 = lane & 15, quad = lane >> 4;
    const int kc = blockIdx.x;
    const int ibase = blockIdx.y * 128 + wid * 32;

    // ---- stage phase-A weights: WpT slice + bpBf slice ----
    for (int c = tid; c < 2560; c += 256) {
        int row = c / 40, off = c % 40;
        short8 v = *(const short8*)&WpT[(size_t)row * NUM_ITEMS + kc * 320 + off * 8];
        *(short8*)&wlds[row * 328 + off * 8] = v;
    }
    if (tid < 40)
        *(short8*)&bpblds[tid * 8] = *(const short8*)&bpBf[kc * 320 + tid * 8];
    __syncthreads();

    // ---------- phase A: x-GEMM (X @ [Wp | bp | ones]) ----------
    float4v acc[2][4], accA[2];
    #pragma unroll
    for (int mt = 0; mt < 2; mt++) {
        accA[mt] = (float4v){0.f, 0.f, 0.f, 0.f};
        #pragma unroll
        for (int nt = 0; nt < 4; nt++) acc[mt][nt] = (float4v){0.f, 0.f, 0.f, 0.f};
    }
    float4 xr[2][2][2];                 // [buf][mt][half] -- all indices compile-time
    #pragma unroll
    for (int mt = 0; mt < 2; mt++) {
        const float* px = x + (size_t)(ibase + mt * 16 + l15) * NUM_ITEMS + kc * 320 + quad * 8;
        xr[0][mt][0] = *(const float4*)px;
        xr[0][mt][1] = *(const float4*)(px + 4);
    }
    #pragma unroll
    for (int st = 0; st < 10; st++) {
        const int cur = st & 1, nxt = cur ^ 1;
        if (st < 9) {                    // 2-deep x prefetch (the only global loads)
            #pragma unroll
            for (int mt = 0; mt < 2; mt++) {
                const float* px = x + (size_t)(ibase + mt * 16 + l15) * NUM_ITEMS
                                    + kc * 320 + (st + 1) * 32 + quad * 8;
                xr[nxt][mt][0] = *(const float4*)px;
                xr[nxt][mt][1] = *(const float4*)(px + 4);
            }
        }
        short8 bfr[4];
        #pragma unroll
        for (int nt = 0; nt < 4; nt++)
            bfr[nt] = *(const short8*)&wlds[(nt * 16 + l15) * 328 + st * 32 + quad * 8];
        short8 ab;
        if (l15 == 0) {
            ab = *(const short8*)&bpblds[st * 32 + quad * 8];
        } else if (l15 == 1) {
            short o = (short)0x3F80;                 // bf16 1.0
            ab = (short8){o, o, o, o, o, o, o, o};
        } else {
            ab = (short8){0, 0, 0, 0, 0, 0, 0, 0};
        }
        short8 af[2];
        #pragma unroll
        for (int mt = 0; mt < 2; mt++) {
            union { short8 s; unsigned u[4]; } v;
            v.u[0] = pack01(xr[cur][mt][0].x, xr[cur][mt][0].y);
            v.u[1] = pack01(xr[cur][mt][0].z, xr[cur][mt][0].w);
            v.u[2] = pack01(xr[cur][mt][1].x, xr[cur][mt][1].y);
            v.u[3] = pack01(xr[cur][mt][1].z, xr[cur][mt][1].w);
            af[mt] = v.s;
        }
        #pragma unroll
        for (int mt = 0; mt < 2; mt++) {
            #pragma unroll
            for (int nt = 0; nt < 4; nt++)
                acc[mt][nt] = __builtin_amdgcn_mfma_f32_16x16x32_bf16(
                    af[mt], bfr[nt], acc[mt][nt], 0, 0, 0);
            accA[mt] = __builtin_amdgcn_mfma_f32_16x16x32_bf16(
                    af[mt], ab, accA[mt], 0, 0, 0);
        }
    }
    // epilogue A: dx = z.Y reduced over l15; sx from ones col; xb from bp col
    float c_s[2][4], sx_s[2][4];
    #pragma unroll
    for (int mt = 0; mt < 2; mt++) {
        #pragma unroll
        for (int r = 0; r < 4; r++) {
            const int row = ibase + mt * 16 + quad * 4 + r;
            float dxp = 0.f;
            #pragma unroll
            for (int nt = 0; nt < 4; nt++)
                dxp += zF32[(size_t)row * EMB + nt * 16 + l15] * acc[mt][nt][r];
            #pragma unroll
            for (int d = 1; d < 16; d <<= 1) dxp += __shfl_xor(dxp, d);
            sx_s[mt][r] = __shfl(accA[mt][r], (lane & 48) + 1);   // col 1 = ones
            c_s[mt][r] = dxp + accA[mt][r];                       // + col 0 (bp) at l15==0
        }
    }

    // ---- re-stage phase-B weights: WpBf slice + bp slice ----
    __syncthreads();                     // phase-A LDS reads complete
    for (int c = tid; c < 2560; c += 256) {
        int row = c >> 3, off = c & 7;
        short8 v = *(const short8*)&WpBf[(size_t)(kc * 320 + row) * 64 + off * 8];
        *(short8*)&wlds[row * 72 + off * 8] = v;
    }
    if (tid < 320) bplds[tid] = bp[kc * 320 + tid];
    __syncthreads();

    // ---------- phase B: z-LSE ----------
    short8 zf[2][2];
    #pragma unroll
    for (int mt = 0; mt < 2; mt++) {
        const unsigned short* pa = zbBf + (size_t)(ibase + mt * 16 + l15) * EMB + quad * 8;
        zf[mt][0] = *(const short8*)pa;
        zf[mt][1] = *(const short8*)(pa + 32);
    }
    float m_run[2][4], s_run[2][4];
    #pragma unroll
    for (int mt = 0; mt < 2; mt++)
        #pragma unroll
        for (int r = 0; r < 4; r++) { m_run[mt][r] = -1e30f; s_run[mt][r] = 0.f; }

    #pragma unroll
    for (int c5 = 0; c5 < 5; c5++) {
        short8 bfr2[4][2];
        #pragma unroll
        for (int nt = 0; nt < 4; nt++) {
            #pragma unroll
            for (int kh = 0; kh < 2; kh++)
                bfr2[nt][kh] = *(const short8*)&wlds[(c5 * 64 + nt * 16 + l15) * 72
                                                     + kh * 32 + quad * 8];
        }
        float4v accz[2][4];
        #pragma unroll
        for (int mt = 0; mt < 2; mt++)
            #pragma unroll
            for (int nt = 0; nt < 4; nt++)
                accz[mt][nt] = (float4v){0.f, 0.f, 0.f, 0.f};
        #pragma unroll
        for (int kh = 0; kh < 2; kh++)
            #pragma unroll
            for (int mt = 0; mt < 2; mt++)
                #pragma unroll
                for (int nt = 0; nt < 4; nt++)
                    accz[mt][nt] = __builtin_amdgcn_mfma_f32_16x16x32_bf16(
                        zf[mt][kh], bfr2[nt][kh], accz[mt][nt], 0, 0, 0);
        float bpv[4];
        #pragma unroll
        for (int nt = 0; nt < 4; nt++) bpv[nt] = bplds[c5 * 64 + nt * 16 + l15];
        #pragma unroll
        for (int mt = 0; mt < 2; mt++) {
            #pragma unroll
            for (int r = 0; r < 4; r++) {
                float v0 = accz[mt][0][r] + bpv[0];
                float v1 = accz[mt][1][r] + bpv[1];
                float v2 = accz[mt][2][r] + bpv[2];
                float v3 = accz[mt][3][r] + bpv[3];
                float mx = fmaxf(fmaxf(v0, v1), fmaxf(v2, v3));
                float M2 = fmaxf(m_run[mt][r], mx);
                float ls = __expf(v0 - M2) + __expf(v1 - M2) +
                           __expf(v2 - M2) + __expf(v3 - M2);
                s_run[mt][r] = s_run[mt][r] * __expf(m_run[mt][r] - M2) + ls;
                m_run[mt][r] = M2;
            }
        }
    }
    #pragma unroll
    for (int d = 1; d < 16; d <<= 1) {
        #pragma unroll
        for (int mt = 0; mt < 2; mt++)
            #pragma unroll
            for (int r = 0; r < 4; r++) {
                float m2 = __shfl_xor(m_run[mt][r], d);
                float s2 = __shfl_xor(s_run[mt][r], d);
                float M = fmaxf(m_run[mt][r], m2);
                s_run[mt][r] = s_run[mt][r] * __expf(m_run[mt][r] - M)
                             + s2 * __expf(m2 - M);
                m_run[mt][r] = M;
            }
    }
    if (l15 == 0) {
        #pragma unroll
        for (int mt = 0; mt < 2; mt++)
            #pragma unroll
            for (int r = 0; r < 4; r++) {
                const int row = ibase + mt * 16 + quad * 4 + r;
                part4[(size_t)row * NCHB + kc] =
                    make_float4(m_run[mt][r], s_run[mt][r], c_s[mt][r], sx_s[mt][r]);
            }
    }
}

// ---------------- merge: lse per row + loss; last block writes out ----------------
__global__ __launch_bounds__(64) void k_merge(const float4* __restrict__ part4,
                                              float* __restrict__ scal,
                                              float* __restrict__ out) {
    const int row = blockIdx.x;
    const int lane = threadIdx.x;
    float M = -1e30f, S = 0.f, dxc = 0.f, sx = 0.f;
    for (int c = lane; c < NCHB; c += 64) {
        float4 p = part4[(size_t)row * NCHB + c];
        float M2 = fmaxf(M, p.x);
        S = S * __expf(M - M2) + p.y * __expf(p.x - M2);
        M = M2; dxc += p.z; sx += p.w;
    }
    #pragma unroll
    for (int o = 1; o < 64; o <<= 1) {
        float M2 = __shfl_xor(M, o);
        float S2 = __shfl_xor(S, o);
        float Mn = fmaxf(M, M2);
        S = S * __expf(M - Mn) + S2 * __expf(M2 - Mn);
        M = Mn;
        dxc += __shfl_xor(dxc, o);
        sx += __shfl_xor(sx, o);
    }
    if (lane == 0) {
        float lse = M + logf(S);
        atomicAdd(&scal[0], dxc - lse * sx);
        __threadfence();
        unsigned done = atomicAdd((unsigned*)&scal[2], 1u);
        if (done == BATCH - 1) {
            float recon = atomicAdd(&scal[0], 0.f);
            float kl = atomicAdd(&scal[1], 0.f);
            out[0] = -recon * (1.0f / BATCH);
            out[1] = -0.5f * kl * (1.0f / BATCH);
        }
    }
}

extern "C" void kernel_launch(void* const* d_in, const int* in_sizes, int n_in,
                              void* d_out, int out_size, void* d_ws, size_t ws_size,
                              hipStream_t stream) {
    const float* graph_vals = (const float*)d_in[0];
    const float* Wq         = (const float*)d_in[1];
    const float* bq         = (const float*)d_in[2];
    const float* Wp         = (const float*)d_in[3];
    const float* bp         = (const float*)d_in[4];
    const float* x          = (const float*)d_in[5];
    const float* eps        = (const float*)d_in[6];
    const int*   graph_rows = (const int*)d_in[7];
    const int*   graph_cols = (const int*)d_in[8];
    const int*   user       = (const int*)d_in[9];
    float* out = (float*)d_out;

    char* ws = (char*)d_ws;
    int*            map     = (int*)(ws + 0);                    //   200,704
    int*            cnt     = (int*)(ws + 200704);               //     4,096
    float*          scal    = (float*)(ws + 204800);             //       256
    int2*           compact = (int2*)(ws + 205056);              // 1,048,576 -> 1,253,632
    unsigned short* zbBf    = (unsigned short*)(ws + 1253632);   //   131,072 -> 1,384,704
    float*          zF32    = (float*)(ws + 1384704);            //   262,144 -> 1,646,848
    float4*         part4   = (float4*)(ws + 1646848);           // 2,048,000 -> 3,694,848
    unsigned short* WpBf    = (unsigned short*)(ws + 3694848);   // 5,120,000 -> 8,814,848
    unsigned short* WqT     = (unsigned short*)(ws + 8814848);   // 10,240,000 -> 19,054,848
    unsigned short* WpT     = (unsigned short*)(ws + 19054848);  // 5,120,000 -> 24,174,848
    unsigned short* bpBf    = (unsigned short*)(ws + 24174848);  //    80,000 -> 24,254,848

    k_init<<<512, 256, 0, stream>>>(map, cnt, scal, compact);
    k_map<<<4, 256, 0, stream>>>(user, map);
    k_prepsc<<<SC_BLK + 4415, 256, 0, stream>>>(graph_rows, graph_cols, graph_vals, map, cnt,
                                                compact, Wq, Wp, bp, WqT, WpBf, WpT, bpBf);
    k_hz<<<BATCH, 256, 0, stream>>>(user, map, cnt, compact, WqT, bq, eps, zbBf, zF32, scal);
    dim3 g(NCHB, 8);
    k_xz<<<g, 256, 0, stream>>>(x, WpT, bpBf, zF32, zbBf, WpBf, bp, part4);
    k_merge<<<BATCH, 64, 0, stream>>>(part4, scal, out);
}